// Round 1
// baseline (264.584 us; speedup 1.0000x reference)
//
#include <hip/hip_runtime.h>
#include <hip/hip_bf16.h>

typedef short bf16x8 __attribute__((ext_vector_type(8)));
typedef float f32x4 __attribute__((ext_vector_type(4)));
typedef __hip_bfloat16 bf16;

// ---------------- weight prep: fp32 -> bf16, transposed to [N][K] ----------------
// ws layout (bf16 elems): qkvT [192][64] @0 ; projT [64][64] @12288 ;
//                         fcT  [256][64] @16384 ; proj2T [64][256] @32768  (96KB)
__global__ void prep_weights(const float* __restrict__ qkv_w,
                             const float* __restrict__ proj_w,
                             const float* __restrict__ fc_w,
                             const float* __restrict__ proj2_w,
                             bf16* __restrict__ ws) {
    int i = blockIdx.x * blockDim.x + threadIdx.x;
    float v;
    if (i < 12288)      { int n = i >> 6,              k = i & 63;    v = qkv_w[k * 192 + n]; }
    else if (i < 16384) { int j = i - 12288, n = j >> 6, k = j & 63;  v = proj_w[k * 64 + n]; }
    else if (i < 32768) { int j = i - 16384, n = j >> 6, k = j & 63;  v = fc_w[k * 256 + n]; }
    else if (i < 49152) { int j = i - 32768, n = j >> 8, k = j & 255; v = proj2_w[k * 64 + n]; }
    else return;
    ws[i] = __float2bfloat16(v);
}

// ---------------- fused transformer block: one workgroup per sample ----------------
// LDS map (bytes):
//   xs    f32 [64][68]   @0      (17408)  residual, fp32
//   hb    bf16[64][72]   @17408  (9216)   LN output (reused LN1/LN2)
//   qkvb  bf16[64][136]  @26624  (17408)  Q cols 0..63, K cols 64..127   } overlaid
//   vT    bf16[64][72]   @44032  (9216)   V transposed [h*16+d][t]       } with hm
//   hm    bf16[64][264]  @26624  (33792)  MLP hidden (gelu out)          }
//   pb    bf16[64][72]   @60416  (9216)   per-wave P rows
//   yb    bf16[64][72]   @69632  (9216)   attention output
// total 78848 B -> 2 blocks/CU (8 waves/CU)
__global__ __launch_bounds__(256, 2)
void gpt_block(const float* __restrict__ x,
               const float* __restrict__ ln1_g, const float* __restrict__ ln1_b,
               const float* __restrict__ qkv_b, const float* __restrict__ proj_b,
               const float* __restrict__ ln2_g, const float* __restrict__ ln2_b,
               const float* __restrict__ fc_b,  const float* __restrict__ proj2_b,
               const bf16* __restrict__ ws,
               float* __restrict__ out) {
    __shared__ __align__(16) char smem[78848];
    float* xs   = (float*)smem;                 // [64][68]
    bf16*  hb   = (bf16*)(smem + 17408);        // [64][72]
    bf16*  qkvb = (bf16*)(smem + 26624);        // [64][136]
    bf16*  vT   = (bf16*)(smem + 44032);        // [64][72]
    bf16*  hm   = (bf16*)(smem + 26624);        // [64][264]
    bf16*  pb   = (bf16*)(smem + 60416);        // [64][72]
    bf16*  yb   = (bf16*)(smem + 69632);        // [64][72]

    const int tid = threadIdx.x;
    const int w   = tid >> 6;        // wave 0..3
    const int l   = tid & 63;        // lane
    const int lr  = l & 15;          // frag row/col within 16
    const int lk  = l >> 4;          // k-block 0..3
    const size_t b = blockIdx.x;
    const float* xb = x + b * 4096;

    // ---- phase 0: load x tile ----
    {
        const float4* src = (const float4*)xb;
        #pragma unroll
        for (int j = 0; j < 4; ++j) {
            int idx  = j * 256 + tid;
            float4 v = src[idx];
            int row  = idx >> 4;
            int col  = (idx & 15) * 4;
            *(float4*)&xs[row * 68 + col] = v;
        }
    }
    __syncthreads();

    // ---- layernorm helper: xs -> hb ----
    auto layer_norm = [&](const float* g, const float* be) {
        int row = w * 16 + (l >> 2);
        int q   = l & 3;
        const float* xr = &xs[row * 68];
        float vals[16];
        float s0 = 0.f, s1 = 0.f;
        #pragma unroll
        for (int cv = 0; cv < 4; ++cv) {
            float4 v4 = *(const float4*)&xr[q * 16 + cv * 4];
            vals[cv*4+0] = v4.x; vals[cv*4+1] = v4.y; vals[cv*4+2] = v4.z; vals[cv*4+3] = v4.w;
            s0 += v4.x + v4.y + v4.z + v4.w;
            s1 += v4.x*v4.x + v4.y*v4.y + v4.z*v4.z + v4.w*v4.w;
        }
        s0 += __shfl_xor(s0, 1); s1 += __shfl_xor(s1, 1);
        s0 += __shfl_xor(s0, 2); s1 += __shfl_xor(s1, 2);
        float mu   = s0 * (1.f / 64.f);
        float var  = s1 * (1.f / 64.f) - mu * mu;
        float rstd = rsqrtf(var + 1e-5f);
        bf16 tmp[16];
        #pragma unroll
        for (int c = 0; c < 16; ++c) {
            int cc = q * 16 + c;
            tmp[c] = __float2bfloat16((vals[c] - mu) * rstd * g[cc] + be[cc]);
        }
        *(uint4*)&hb[row * 72 + q * 16]     = *(uint4*)&tmp[0];
        *(uint4*)&hb[row * 72 + q * 16 + 8] = *(uint4*)&tmp[8];
    };

    // ---- phase 1: LN1 ----
    layer_norm(ln1_g, ln1_b);
    __syncthreads();

    // ---- phase 2: QKV ----
    {
        const short* wq = (const short*)ws;                    // qkvT [192][64]
        #pragma unroll
        for (int t = 0; t < 3; ++t) {
            int nt = w + t * 4;
            bf16x8 bfr[2];
            #pragma unroll
            for (int ks = 0; ks < 2; ++ks)
                bfr[ks] = *(const bf16x8*)(wq + (nt * 16 + lr) * 64 + ks * 32 + lk * 8);
            float bias = qkv_b[nt * 16 + lr];
            #pragma unroll
            for (int mt = 0; mt < 4; ++mt) {
                f32x4 acc = {};
                #pragma unroll
                for (int ks = 0; ks < 2; ++ks) {
                    bf16x8 a = *(const bf16x8*)((const short*)hb + (mt * 16 + lr) * 72 + ks * 32 + lk * 8);
                    acc = __builtin_amdgcn_mfma_f32_16x16x32_bf16(a, bfr[ks], acc, 0, 0, 0);
                }
                #pragma unroll
                for (int r = 0; r < 4; ++r) {
                    int m = mt * 16 + lk * 4 + r;
                    bf16 v = __float2bfloat16(acc[r] + bias);
                    if (t < 2) qkvb[m * 136 + t * 64 + w * 16 + lr] = v;   // Q | K
                    else       vT[(w * 16 + lr) * 72 + m] = v;             // V^T
                }
            }
        }
    }
    __syncthreads();

    // ---- phase 3: attention (wave w owns query rows 16w..16w+15, all heads) ----
    {
        #pragma unroll
        for (int h = 0; h < 4; ++h) {
            bf16x8 qa = {};
            if (lk < 2)
                qa = *(const bf16x8*)((const short*)qkvb + (w * 16 + lr) * 136 + h * 16 + lk * 8);
            f32x4 s[4];
            #pragma unroll
            for (int nt = 0; nt < 4; ++nt) {
                bf16x8 kb = {};
                if (lk < 2)
                    kb = *(const bf16x8*)((const short*)qkvb + (nt * 16 + lr) * 136 + 64 + h * 16 + lk * 8);
                f32x4 acc = {};
                s[nt] = __builtin_amdgcn_mfma_f32_16x16x32_bf16(qa, kb, acc, 0, 0, 0);
            }
            float p[4][4];
            float rmax[4] = {-1e30f, -1e30f, -1e30f, -1e30f};
            #pragma unroll
            for (int nt = 0; nt < 4; ++nt)
                #pragma unroll
                for (int r = 0; r < 4; ++r) {
                    int qq = w * 16 + lk * 4 + r;
                    int kk = nt * 16 + lr;
                    float v = (kk <= qq) ? s[nt][r] * 0.25f : -1e30f;
                    p[nt][r] = v;
                    rmax[r] = fmaxf(rmax[r], v);
                }
            #pragma unroll
            for (int r = 0; r < 4; ++r) {
                float m_ = rmax[r];
                m_ = fmaxf(m_, __shfl_xor(m_, 1));
                m_ = fmaxf(m_, __shfl_xor(m_, 2));
                m_ = fmaxf(m_, __shfl_xor(m_, 4));
                m_ = fmaxf(m_, __shfl_xor(m_, 8));
                rmax[r] = m_;
            }
            float rsum[4] = {0.f, 0.f, 0.f, 0.f};
            #pragma unroll
            for (int nt = 0; nt < 4; ++nt)
                #pragma unroll
                for (int r = 0; r < 4; ++r) {
                    float e = __expf(p[nt][r] - rmax[r]);
                    p[nt][r] = e;
                    rsum[r] += e;
                }
            #pragma unroll
            for (int r = 0; r < 4; ++r) {
                float s_ = rsum[r];
                s_ += __shfl_xor(s_, 1);
                s_ += __shfl_xor(s_, 2);
                s_ += __shfl_xor(s_, 4);
                s_ += __shfl_xor(s_, 8);
                rsum[r] = 1.f / s_;
            }
            #pragma unroll
            for (int nt = 0; nt < 4; ++nt)
                #pragma unroll
                for (int r = 0; r < 4; ++r)
                    pb[(w * 16 + lk * 4 + r) * 72 + nt * 16 + lr] = __float2bfloat16(p[nt][r] * rsum[r]);
            f32x4 y = {};
            #pragma unroll
            for (int ks = 0; ks < 2; ++ks) {
                bf16x8 a  = *(const bf16x8*)((const short*)pb + (w * 16 + lr) * 72 + ks * 32 + lk * 8);
                bf16x8 vb = *(const bf16x8*)((const short*)vT + (h * 16 + lr) * 72 + ks * 32 + lk * 8);
                y = __builtin_amdgcn_mfma_f32_16x16x32_bf16(a, vb, y, 0, 0, 0);
            }
            #pragma unroll
            for (int r = 0; r < 4; ++r)
                yb[(w * 16 + lk * 4 + r) * 72 + h * 16 + lr] = __float2bfloat16(y[r]);
        }
    }
    __syncthreads();

    // ---- phase 4: proj + residual -> xs ----
    {
        const short* wp = (const short*)ws + 12288;             // projT [64][64]
        bf16x8 bfr[2];
        #pragma unroll
        for (int ks = 0; ks < 2; ++ks)
            bfr[ks] = *(const bf16x8*)(wp + (w * 16 + lr) * 64 + ks * 32 + lk * 8);
        float bias = proj_b[w * 16 + lr];
        #pragma unroll
        for (int mt = 0; mt < 4; ++mt) {
            f32x4 acc = {};
            #pragma unroll
            for (int ks = 0; ks < 2; ++ks) {
                bf16x8 a = *(const bf16x8*)((const short*)yb + (mt * 16 + lr) * 72 + ks * 32 + lk * 8);
                acc = __builtin_amdgcn_mfma_f32_16x16x32_bf16(a, bfr[ks], acc, 0, 0, 0);
            }
            #pragma unroll
            for (int r = 0; r < 4; ++r) {
                int row = mt * 16 + lk * 4 + r, col = w * 16 + lr;
                xs[row * 68 + col] += acc[r] + bias;
            }
        }
    }
    __syncthreads();

    // ---- phase 5: LN2 ----
    layer_norm(ln2_g, ln2_b);
    __syncthreads();

    // ---- phase 6: fc + exact gelu -> hm ----
    {
        const short* wf = (const short*)ws + 16384;             // fcT [256][64]
        #pragma unroll
        for (int t = 0; t < 4; ++t) {
            int nt = w + t * 4;
            bf16x8 bfr[2];
            #pragma unroll
            for (int ks = 0; ks < 2; ++ks)
                bfr[ks] = *(const bf16x8*)(wf + (nt * 16 + lr) * 64 + ks * 32 + lk * 8);
            float bias = fc_b[nt * 16 + lr];
            #pragma unroll
            for (int mt = 0; mt < 4; ++mt) {
                f32x4 acc = {};
                #pragma unroll
                for (int ks = 0; ks < 2; ++ks) {
                    bf16x8 a = *(const bf16x8*)((const short*)hb + (mt * 16 + lr) * 72 + ks * 32 + lk * 8);
                    acc = __builtin_amdgcn_mfma_f32_16x16x32_bf16(a, bfr[ks], acc, 0, 0, 0);
                }
                #pragma unroll
                for (int r = 0; r < 4; ++r) {
                    float v  = acc[r] + bias;
                    float ge = 0.5f * v * (1.f + erff(v * 0.70710678118f));
                    hm[(mt * 16 + lk * 4 + r) * 264 + nt * 16 + lr] = __float2bfloat16(ge);
                }
            }
        }
    }
    __syncthreads();

    // ---- phase 7: proj2 + residual -> out ----
    {
        const short* wp2 = (const short*)ws + 32768;            // proj2T [64][256]
        bf16x8 bfr[8];
        #pragma unroll
        for (int ks = 0; ks < 8; ++ks)
            bfr[ks] = *(const bf16x8*)(wp2 + (w * 16 + lr) * 256 + ks * 32 + lk * 8);
        float bias = proj2_b[w * 16 + lr];
        float* ob = out + b * 4096;
        #pragma unroll
        for (int mt = 0; mt < 4; ++mt) {
            f32x4 acc = {};
            #pragma unroll
            for (int ks = 0; ks < 8; ++ks) {
                bf16x8 a = *(const bf16x8*)((const short*)hm + (mt * 16 + lr) * 264 + ks * 32 + lk * 8);
                acc = __builtin_amdgcn_mfma_f32_16x16x32_bf16(a, bfr[ks], acc, 0, 0, 0);
            }
            #pragma unroll
            for (int r = 0; r < 4; ++r) {
                int row = mt * 16 + lk * 4 + r, col = w * 16 + lr;
                ob[row * 64 + col] = xs[row * 68 + col] + acc[r] + bias;
            }
        }
    }
}

extern "C" void kernel_launch(void* const* d_in, const int* in_sizes, int n_in,
                              void* d_out, int out_size, void* d_ws, size_t ws_size,
                              hipStream_t stream) {
    const float* x       = (const float*)d_in[0];
    const float* ln1_g   = (const float*)d_in[1];
    const float* ln1_b   = (const float*)d_in[2];
    const float* qkv_w   = (const float*)d_in[3];
    const float* qkv_b   = (const float*)d_in[4];
    const float* proj_w  = (const float*)d_in[5];
    const float* proj_b  = (const float*)d_in[6];
    const float* ln2_g   = (const float*)d_in[7];
    const float* ln2_b   = (const float*)d_in[8];
    const float* fc_w    = (const float*)d_in[9];
    const float* fc_b    = (const float*)d_in[10];
    const float* proj2_w = (const float*)d_in[11];
    const float* proj2_b = (const float*)d_in[12];
    bf16* ws  = (bf16*)d_ws;
    float* out = (float*)d_out;

    prep_weights<<<192, 256, 0, stream>>>(qkv_w, proj_w, fc_w, proj2_w, ws);
    gpt_block<<<4096, 256, 0, stream>>>(x, ln1_g, ln1_b, qkv_b, proj_b,
                                        ln2_g, ln2_b, fc_b, proj2_b, ws, out);
}

// Round 3
// 244.135 us; speedup vs baseline: 1.0838x; 1.0838x over previous
//
#include <hip/hip_runtime.h>
#include <hip/hip_bf16.h>

typedef short bf16x8 __attribute__((ext_vector_type(8)));
typedef short bf16x4 __attribute__((ext_vector_type(4)));
typedef float f32x4  __attribute__((ext_vector_type(4)));
typedef __hip_bfloat16 bf16;

static __device__ __forceinline__ short f2bf(float x) {
    bf16 t = __float2bfloat16(x);
    return *reinterpret_cast<short*>(&t);
}

// ---------------- weight prep: fp32 -> bf16, transposed to [N][K] ----------------
// ws (bf16 elems): qkvT [192][64] @0 ; projT [64][64] @12288 ;
//                  fcT  [256][64] @16384 ; proj2T [64][256] @32768   (96 KB)
__global__ void prep_weights(const float* __restrict__ qkv_w,
                             const float* __restrict__ proj_w,
                             const float* __restrict__ fc_w,
                             const float* __restrict__ proj2_w,
                             bf16* __restrict__ ws) {
    int i = blockIdx.x * blockDim.x + threadIdx.x;
    float v;
    if (i < 12288)      { int n = i >> 6,              k = i & 63;    v = qkv_w[k * 192 + n]; }
    else if (i < 16384) { int j = i - 12288, n = j >> 6, k = j & 63;  v = proj_w[k * 64 + n]; }
    else if (i < 32768) { int j = i - 16384, n = j >> 6, k = j & 63;  v = fc_w[k * 256 + n]; }
    else if (i < 49152) { int j = i - 32768, n = j >> 8, k = j & 255; v = proj2_w[k * 64 + n]; }
    else return;
    ws[i] = __float2bfloat16(v);
}

// ---------------- fused transformer block: one workgroup per sample ----------------
// LDS (35840 B -> 4 blocks/CU):
//   hb  bf16[64][72]  @0      (9216)  LN out; aliased by pb (attention P) in phase3
//   qk  bf16[64][136] @9216   (17408) cols 0-63: Q -> y (in-place), cols 64-127: K
//   vT  bf16[64][72]  @26624  (9216)  V transposed [h*16+d][t]
//   hm  bf16[64][136] @9216           MLP hidden half (overlays qk after phase4)
__global__ __launch_bounds__(256, 4)
void gpt_block(const float* __restrict__ x,
               const float* __restrict__ ln1_g, const float* __restrict__ ln1_b,
               const float* __restrict__ qkv_b, const float* __restrict__ proj_b,
               const float* __restrict__ ln2_g, const float* __restrict__ ln2_b,
               const float* __restrict__ fc_b,  const float* __restrict__ proj2_b,
               const bf16* __restrict__ ws,
               float* __restrict__ out) {
    __shared__ __align__(16) char smem[35840];
    bf16* hb = (bf16*)smem;             // [64][72]
    bf16* pb = hb;                      // alias, phase3 only
    bf16* qk = (bf16*)(smem + 9216);    // [64][136]
    bf16* vT = (bf16*)(smem + 26624);   // [64][72]
    bf16* hm = (bf16*)(smem + 9216);    // [64][136], overlays qk

    const int tid = threadIdx.x;
    const int w   = tid >> 6;          // wave 0..3
    const int l   = tid & 63;
    const int lr  = l & 15;
    const int lk  = l >> 4;
    const int row = w * 16 + lr;       // token row this lane owns on the B side
    const size_t b = blockIdx.x;

    // ---- phase 0: x tile -> registers (float4, fully coalesced) ----
    f32x4 xr[4];
    {
        const float* xb = x + b * 4096;
        #pragma unroll
        for (int nt = 0; nt < 4; ++nt)
            xr[nt] = *(const f32x4*)&xb[row * 64 + nt * 16 + lk * 4];
    }

    // ---- layernorm on register residual -> hb ----
    auto ln = [&](const float* g, const float* be) {
        float s0 = 0.f, s1 = 0.f;
        #pragma unroll
        for (int nt = 0; nt < 4; ++nt)
            #pragma unroll
            for (int r = 0; r < 4; ++r) { float v = xr[nt][r]; s0 += v; s1 += v * v; }
        s0 += __shfl_xor(s0, 16); s1 += __shfl_xor(s1, 16);
        s0 += __shfl_xor(s0, 32); s1 += __shfl_xor(s1, 32);
        float mu   = s0 * (1.f / 64.f);
        float var  = s1 * (1.f / 64.f) - mu * mu;
        float rstd = rsqrtf(var + 1e-5f);
        #pragma unroll
        for (int nt = 0; nt < 4; ++nt) {
            f32x4 g4 = ((const f32x4*)g)[nt * 4 + lk];
            f32x4 b4 = ((const f32x4*)be)[nt * 4 + lk];
            bf16x4 o;
            #pragma unroll
            for (int r = 0; r < 4; ++r)
                o[r] = f2bf((xr[nt][r] - mu) * rstd * g4[r] + b4[r]);
            *(bf16x4*)&hb[row * 72 + nt * 16 + lk * 4] = o;
        }
    };

    ln(ln1_g, ln1_b);
    __syncthreads();

    // ---- phase 2: QKV (A=W feature-side for Q/K, A=act for V -> all packed stores) ----
    {
        const short* wsb = (const short*)ws;
        bf16x8 hbf[4][2];
        #pragma unroll
        for (int mt = 0; mt < 4; ++mt)
            #pragma unroll
            for (int ks = 0; ks < 2; ++ks)
                hbf[mt][ks] = *(const bf16x8*)((const short*)hb + (mt * 16 + lr) * 72 + ks * 32 + lk * 8);

        bf16x8 aq[2], ak[2], bv[2];
        #pragma unroll
        for (int ks = 0; ks < 2; ++ks) {
            aq[ks] = *(const bf16x8*)(wsb + (w * 16 + lr) * 64        + ks * 32 + lk * 8);
            ak[ks] = *(const bf16x8*)(wsb + (64 + w * 16 + lr) * 64   + ks * 32 + lk * 8);
            bv[ks] = *(const bf16x8*)(wsb + (128 + w * 16 + lr) * 64  + ks * 32 + lk * 8);
        }
        f32x4 qb = ((const f32x4*)qkv_b)[w * 4 + lk];
        f32x4 kb = ((const f32x4*)qkv_b)[16 + w * 4 + lk];
        float vbias = qkv_b[128 + w * 16 + lr];

        #pragma unroll
        for (int mt = 0; mt < 4; ++mt) {                    // Q: D[f][token]
            f32x4 acc = {};
            #pragma unroll
            for (int ks = 0; ks < 2; ++ks)
                acc = __builtin_amdgcn_mfma_f32_16x16x32_bf16(aq[ks], hbf[mt][ks], acc, 0, 0, 0);
            bf16x4 o;
            #pragma unroll
            for (int r = 0; r < 4; ++r) o[r] = f2bf(acc[r] + qb[r]);
            *(bf16x4*)&qk[(mt * 16 + lr) * 136 + w * 16 + lk * 4] = o;
        }
        #pragma unroll
        for (int mt = 0; mt < 4; ++mt) {                    // K
            f32x4 acc = {};
            #pragma unroll
            for (int ks = 0; ks < 2; ++ks)
                acc = __builtin_amdgcn_mfma_f32_16x16x32_bf16(ak[ks], hbf[mt][ks], acc, 0, 0, 0);
            bf16x4 o;
            #pragma unroll
            for (int r = 0; r < 4; ++r) o[r] = f2bf(acc[r] + kb[r]);
            *(bf16x4*)&qk[(mt * 16 + lr) * 136 + 64 + w * 16 + lk * 4] = o;
        }
        #pragma unroll
        for (int mt = 0; mt < 4; ++mt) {                    // V: D[token][f] -> vT packed
            f32x4 acc = {};
            #pragma unroll
            for (int ks = 0; ks < 2; ++ks)
                acc = __builtin_amdgcn_mfma_f32_16x16x32_bf16(hbf[mt][ks], bv[ks], acc, 0, 0, 0);
            bf16x4 o;
            #pragma unroll
            for (int r = 0; r < 4; ++r) o[r] = f2bf(acc[r] + vbias);
            *(bf16x4*)&vT[(w * 16 + lr) * 72 + mt * 16 + lk * 4] = o;
        }
    }
    __syncthreads();

    // ---- phase 3: attention (S^T in regs; causal tile-skip; y in-place over Q) ----
    {
        bf16x4 z = {};
        for (int kt = w + 1; kt < 4; ++kt)                  // zero P tail once
            *(bf16x4*)&pb[row * 72 + kt * 16 + lk * 4] = z;

        #pragma unroll
        for (int h = 0; h < 4; ++h) {
            bf16x8 qf = {};
            if (lk < 2)
                qf = *(const bf16x8*)((const short*)qk + row * 136 + h * 16 + lk * 8);
            float pr[4][4];
            float psum = 0.f;
            for (int kt = 0; kt <= w; ++kt) {               // wave-uniform trip count
                bf16x8 kf = {};
                if (lk < 2)
                    kf = *(const bf16x8*)((const short*)qk + (kt * 16 + lr) * 136 + 64 + h * 16 + lk * 8);
                f32x4 acc = {};
                f32x4 sv = __builtin_amdgcn_mfma_f32_16x16x32_bf16(kf, qf, acc, 0, 0, 0);
                #pragma unroll
                for (int r = 0; r < 4; ++r) {
                    float s = sv[r] * 0.25f;
                    if (kt == w && (4 * lk + r) > lr) s = -1e30f;   // causal mask on diag tile
                    float e = __expf(s);
                    pr[kt][r] = e; psum += e;
                }
            }
            psum += __shfl_xor(psum, 16);
            psum += __shfl_xor(psum, 32);
            float rinv = __builtin_amdgcn_rcpf(psum);
            for (int kt = 0; kt <= w; ++kt) {
                bf16x4 o;
                #pragma unroll
                for (int r = 0; r < 4; ++r) o[r] = f2bf(pr[kt][r] * rinv);
                *(bf16x4*)&pb[row * 72 + kt * 16 + lk * 4] = o;
            }
            // PV: A=vT (d rows), B=P (q rows) -> D[d][q] -> packed into y[q][h*16+d]
            f32x4 y = {};
            #pragma unroll
            for (int ks = 0; ks < 2; ++ks) {
                bf16x8 vf = *(const bf16x8*)((const short*)vT + (h * 16 + lr) * 72 + ks * 32 + lk * 8);
                bf16x8 pf = *(const bf16x8*)((const short*)pb + row * 72 + ks * 32 + lk * 8);
                y = __builtin_amdgcn_mfma_f32_16x16x32_bf16(vf, pf, y, 0, 0, 0);
            }
            bf16x4 o;
            #pragma unroll
            for (int r = 0; r < 4; ++r) o[r] = f2bf(y[r]);
            *(bf16x4*)&qk[row * 136 + h * 16 + lk * 4] = o;     // overwrite dead Q cols
        }
    }
    // no barrier needed: phase 4 reads only this wave's own y rows

    // ---- phase 4: attn proj + residual into registers ----
    {
        const short* wp = (const short*)ws + 12288;
        bf16x8 yf[2];
        #pragma unroll
        for (int ks = 0; ks < 2; ++ks)
            yf[ks] = *(const bf16x8*)((const short*)qk + row * 136 + ks * 32 + lk * 8);
        #pragma unroll
        for (int nt = 0; nt < 4; ++nt) {
            f32x4 acc = {};
            #pragma unroll
            for (int ks = 0; ks < 2; ++ks) {
                bf16x8 a = *(const bf16x8*)(wp + (nt * 16 + lr) * 64 + ks * 32 + lk * 8);
                acc = __builtin_amdgcn_mfma_f32_16x16x32_bf16(a, yf[ks], acc, 0, 0, 0);
            }
            f32x4 pb4 = ((const f32x4*)proj_b)[nt * 4 + lk];
            #pragma unroll
            for (int r = 0; r < 4; ++r) xr[nt][r] += acc[r] + pb4[r];
        }
    }
    __syncthreads();        // qk fully consumed; hm may overlay it now

    // ---- phase 5: LN2 ----
    ln(ln2_g, ln2_b);
    __syncthreads();

    // ---- phases 6/7: MLP in two feature halves (hm = half-size buffer over qk) ----
    f32x4 acc2[4] = {f32x4{}, f32x4{}, f32x4{}, f32x4{}};
    {
        const short* wf = (const short*)ws + 16384;
        const short* w2 = (const short*)ws + 32768;
        for (int H = 0; H < 2; ++H) {
            #pragma unroll
            for (int u = 0; u < 2; ++u) {                   // fc half: tiles {w, w+4}
                int lt = w + u * 4;
                int gt = H * 8 + lt;
                bf16x8 af[2];
                #pragma unroll
                for (int ks = 0; ks < 2; ++ks)
                    af[ks] = *(const bf16x8*)(wf + (gt * 16 + lr) * 64 + ks * 32 + lk * 8);
                f32x4 fb = ((const f32x4*)fc_b)[gt * 4 + lk];
                #pragma unroll
                for (int mt = 0; mt < 4; ++mt) {
                    f32x4 acc = {};
                    #pragma unroll
                    for (int ks = 0; ks < 2; ++ks) {
                        bf16x8 hf = *(const bf16x8*)((const short*)hb + (mt * 16 + lr) * 72 + ks * 32 + lk * 8);
                        acc = __builtin_amdgcn_mfma_f32_16x16x32_bf16(af[ks], hf, acc, 0, 0, 0);
                    }
                    bf16x4 o;
                    #pragma unroll
                    for (int r = 0; r < 4; ++r) {
                        float v = acc[r] + fb[r];
                        float u_ = v * (0.7978845608f + 0.0356774081f * v * v);
                        u_ = fminf(u_, 8.f);
                        float e = __expf(2.f * u_);
                        float ge = v * e * __builtin_amdgcn_rcpf(1.f + e);
                        o[r] = f2bf(ge);
                    }
                    *(bf16x4*)&hm[(mt * 16 + lr) * 136 + lt * 16 + lk * 4] = o;
                }
            }
            __syncthreads();                                // hm half visible
            bf16x8 hf4[4];
            #pragma unroll
            for (int ks = 0; ks < 4; ++ks)
                hf4[ks] = *(const bf16x8*)((const short*)hm + row * 136 + ks * 32 + lk * 8);
            #pragma unroll
            for (int nt = 0; nt < 4; ++nt) {
                #pragma unroll
                for (int ks = 0; ks < 4; ++ks) {
                    bf16x8 a = *(const bf16x8*)(w2 + (nt * 16 + lr) * 256 + H * 128 + ks * 32 + lk * 8);
                    acc2[nt] = __builtin_amdgcn_mfma_f32_16x16x32_bf16(a, hf4[ks], acc2[nt], 0, 0, 0);
                }
            }
            if (H == 0) __syncthreads();                    // before fc overwrites hm
        }
    }

    // ---- epilogue: out = residual + proj2 + bias (float4 stores) ----
    {
        float* ob = out + b * 4096;
        #pragma unroll
        for (int nt = 0; nt < 4; ++nt) {
            f32x4 b2 = ((const f32x4*)proj2_b)[nt * 4 + lk];
            f32x4 o;
            #pragma unroll
            for (int r = 0; r < 4; ++r) o[r] = xr[nt][r] + acc2[nt][r] + b2[r];
            *(f32x4*)&ob[row * 64 + nt * 16 + lk * 4] = o;
        }
    }
}

extern "C" void kernel_launch(void* const* d_in, const int* in_sizes, int n_in,
                              void* d_out, int out_size, void* d_ws, size_t ws_size,
                              hipStream_t stream) {
    const float* x       = (const float*)d_in[0];
    const float* ln1_g   = (const float*)d_in[1];
    const float* ln1_b   = (const float*)d_in[2];
    const float* qkv_w   = (const float*)d_in[3];
    const float* qkv_b   = (const float*)d_in[4];
    const float* proj_w  = (const float*)d_in[5];
    const float* proj_b  = (const float*)d_in[6];
    const float* ln2_g   = (const float*)d_in[7];
    const float* ln2_b   = (const float*)d_in[8];
    const float* fc_w    = (const float*)d_in[9];
    const float* fc_b    = (const float*)d_in[10];
    const float* proj2_w = (const float*)d_in[11];
    const float* proj2_b = (const float*)d_in[12];
    bf16* ws   = (bf16*)d_ws;
    float* out = (float*)d_out;

    prep_weights<<<192, 256, 0, stream>>>(qkv_w, proj_w, fc_w, proj2_w, ws);
    gpt_block<<<4096, 256, 0, stream>>>(x, ln1_g, ln1_b, qkv_b, proj_b,
                                        ln2_g, ln2_b, fc_b, proj2_b, ws, out);
}